// Round 12
// baseline (568.912 us; speedup 1.0000x reference)
//
#include <hip/hip_runtime.h>
#include <hip/hip_bf16.h>
#include <math.h>

// ---------------- graph structure ----------------

__global__ void count_indeg(const int* __restrict__ dst, int e, int* __restrict__ indeg) {
    int i = blockIdx.x * blockDim.x + threadIdx.x;
    if (i < e) atomicAdd(&indeg[dst[i]], 1);
}

// fused setup: dinv + ranges + nodeW table (i < n)  |  weight fake-quant (i < nW)
__global__ void setup_misc(const int* __restrict__ indeg, float* __restrict__ dinv,
                           int* __restrict__ start, int* __restrict__ cursor,
                           int* __restrict__ counter,
                           const float* __restrict__ g2, const float* __restrict__ g3,
                           float4* __restrict__ nodeW, int n,
                           const float* __restrict__ W1, const float* __restrict__ a1,
                           const float* __restrict__ W2, const float* __restrict__ a2,
                           const float* __restrict__ W3, const float* __restrict__ a3,
                           float* __restrict__ w1q, float* __restrict__ w2q,
                           float* __restrict__ w3q, int n1, int n2, int n3) {
    int i = blockIdx.x * blockDim.x + threadIdx.x;
    if (i < n) {
        int d = indeg[i];
        float ds = 1.0f / sqrtf((float)(d + 1));
        dinv[i] = ds;
        nodeW[i] = make_float4(ds, ds * g2[i], ds * g3[i], 0.0f);
        int s = atomicAdd(counter, d);
        start[i] = s;
        cursor[i] = s;
    }
    const float* w; const float* a; float* o; int k;
    if (i < n1) { w = W1; a = a1; o = w1q; k = i; }
    else if (i < n1 + n2) { w = W2; a = a2; o = w2q; k = i - n1; }
    else if (i < n1 + n2 + n3) { w = W3; a = a3; o = w3q; k = i - n1 - n2; }
    else return;
    float s = a[0];
    float v = w[k] / s;
    v = fminf(fmaxf(v, -8.0f), 7.0f);
    o[k] = rintf(v) * s;   // round-half-even, matches jnp.round
}

// minimal CSR fill: one atomic + one 4B store per edge
__global__ void fill_csr_min(const int* __restrict__ src, const int* __restrict__ dst,
                             int e, int* __restrict__ cursor, int* __restrict__ ssrc, int n) {
    int i = blockIdx.x * blockDim.x + threadIdx.x;
    if (i >= e) return;
    int s = src[i];
    int p = atomicAdd(&cursor[dst[i]], 1);
    if (p >= 0 && p < e) ssrc[p] = ((unsigned)s < (unsigned)n) ? s : -1;
}

// ---------------- GEMM 128-col + optional fused BN-stats partials ----------------

__global__ __launch_bounds__(256) void gemm128_bias(
        const float* __restrict__ A, const float* __restrict__ B,
        const float* __restrict__ bias,
        const float* __restrict__ dinv, const float* __restrict__ colsumS,
        float* __restrict__ C, float* __restrict__ statsP, int M, int K) {
    __shared__ float sA[16][132];
    __shared__ float sB[16][132];
    int tid = threadIdx.x;
    int rowBase = blockIdx.x * 128;
    int tx = tid & 15;
    int ty = tid >> 4;
    float acc[8][8] = {};

    int aRow = tid >> 1;
    int aK   = (tid & 1) * 8;
    int bK   = tid >> 4;
    int bCol = (tid & 15) * 8;

    for (int k0 = 0; k0 < K; k0 += 16) {
        int gRow = rowBase + aRow;
        if (gRow >= M) gRow = M - 1;
        const float* ap = A + (size_t)gRow * K + k0 + aK;
        float4 a0 = *(const float4*)ap;
        float4 a1 = *(const float4*)(ap + 4);
        sA[aK + 0][aRow] = a0.x;
        sA[aK + 1][aRow] = a0.y;
        sA[aK + 2][aRow] = a0.z;
        sA[aK + 3][aRow] = a0.w;
        sA[aK + 4][aRow] = a1.x;
        sA[aK + 5][aRow] = a1.y;
        sA[aK + 6][aRow] = a1.z;
        sA[aK + 7][aRow] = a1.w;
        const float* bp = B + (size_t)(k0 + bK) * 128 + bCol;
        *(float4*)&sB[bK][bCol]     = *(const float4*)bp;
        *(float4*)&sB[bK][bCol + 4] = *(const float4*)(bp + 4);
        __syncthreads();

#pragma unroll
        for (int kk = 0; kk < 16; ++kk) {
            float4 av0 = *(const float4*)&sA[kk][ty * 8];
            float4 av1 = *(const float4*)&sA[kk][ty * 8 + 4];
            float4 bv0 = *(const float4*)&sB[kk][tx * 4];
            float4 bv1 = *(const float4*)&sB[kk][64 + tx * 4];
            float a[8] = {av0.x, av0.y, av0.z, av0.w, av1.x, av1.y, av1.z, av1.w};
            float b[8] = {bv0.x, bv0.y, bv0.z, bv0.w, bv1.x, bv1.y, bv1.z, bv1.w};
#pragma unroll
            for (int i = 0; i < 8; ++i)
#pragma unroll
                for (int j = 0; j < 8; ++j)
                    acc[i][j] = fmaf(a[i], b[j], acc[i][j]);
        }
        __syncthreads();
    }

    int c0 = tx * 4, c1 = 64 + tx * 4;
    float bb[8];
#pragma unroll
    for (int j = 0; j < 4; ++j) { bb[j] = bias[c0 + j]; bb[4 + j] = bias[c1 + j]; }
    float s1[8] = {}, s2[8] = {};
#pragma unroll
    for (int i = 0; i < 8; ++i) {
        int row = rowBase + ty * 8 + i;
        if (row >= M) continue;
        float rs = 1.0f;
        if (dinv) { float di = dinv[row]; rs = di * di + colsumS[row]; }
        float v[8];
#pragma unroll
        for (int j = 0; j < 8; ++j) {
            v[j] = acc[i][j] + rs * bb[j];
            s1[j] += v[j];
            s2[j] += v[j] * v[j];
        }
        *(float4*)&C[(size_t)row * 128 + c0] = *(float4*)&v[0];
        *(float4*)&C[(size_t)row * 128 + c1] = *(float4*)&v[4];
    }
    if (statsP) {
        float* sp = statsP + (blockIdx.x & 63) * 256;
#pragma unroll
        for (int j = 0; j < 4; ++j) { sA[ty][c0 + j] = s1[j]; sA[ty][c1 + j] = s1[4 + j]; }
        __syncthreads();
        if (tid < 128) {
            float t = 0.f;
#pragma unroll
            for (int k = 0; k < 16; ++k) t += sA[k][tid];
            atomicAdd(&sp[tid], t);
        }
        __syncthreads();
#pragma unroll
        for (int j = 0; j < 4; ++j) { sA[ty][c0 + j] = s2[j]; sA[ty][c1 + j] = s2[4 + j]; }
        __syncthreads();
        if (tid < 128) {
            float t = 0.f;
#pragma unroll
            for (int k = 0; k < 16; ++k) t += sA[k][tid];
            atomicAdd(&sp[128 + tid], t);
        }
    }
}

// ---------------- layer-3 GEMM (N<=64) + fused log_softmax ----------------

__global__ __launch_bounds__(256) void gemm40_softmax(
        const float* __restrict__ A, const float* __restrict__ B,
        const float* __restrict__ bias,
        const float* __restrict__ dinv, const float* __restrict__ colsumS,
        float* __restrict__ out, int M, int N, int K) {
    __shared__ float sA[16][132];
    __shared__ float sB[16][68];
    __shared__ float sOut[128][41];
    int tid = threadIdx.x;
    int rowBase = blockIdx.x * 128;
    int tx = tid & 15;
    int ty = tid >> 4;
    float acc[8][4] = {};

    int aRow = tid >> 1;
    int aK   = (tid & 1) * 8;
    int bK   = tid >> 4;
    int bCol = (tid & 15) * 4;

    for (int k0 = 0; k0 < K; k0 += 16) {
        int gRow = rowBase + aRow;
        if (gRow >= M) gRow = M - 1;
        const float* ap = A + (size_t)gRow * K + k0 + aK;
        float4 a0 = *(const float4*)ap;
        float4 a1 = *(const float4*)(ap + 4);
        sA[aK + 0][aRow] = a0.x;
        sA[aK + 1][aRow] = a0.y;
        sA[aK + 2][aRow] = a0.z;
        sA[aK + 3][aRow] = a0.w;
        sA[aK + 4][aRow] = a1.x;
        sA[aK + 5][aRow] = a1.y;
        sA[aK + 6][aRow] = a1.z;
        sA[aK + 7][aRow] = a1.w;
#pragma unroll
        for (int j = 0; j < 4; ++j) {
            int col = bCol + j;
            sB[bK][col] = (col < N) ? B[(size_t)(k0 + bK) * N + col] : 0.0f;
        }
        __syncthreads();
#pragma unroll
        for (int kk = 0; kk < 16; ++kk) {
            float4 av0 = *(const float4*)&sA[kk][ty * 8];
            float4 av1 = *(const float4*)&sA[kk][ty * 8 + 4];
            float4 bv  = *(const float4*)&sB[kk][tx * 4];
            float a[8] = {av0.x, av0.y, av0.z, av0.w, av1.x, av1.y, av1.z, av1.w};
            float b[4] = {bv.x, bv.y, bv.z, bv.w};
#pragma unroll
            for (int i = 0; i < 8; ++i)
#pragma unroll
                for (int j = 0; j < 4; ++j)
                    acc[i][j] = fmaf(a[i], b[j], acc[i][j]);
        }
        __syncthreads();
    }

    int colOut = tx * 4;
    float bb[4];
#pragma unroll
    for (int j = 0; j < 4; ++j) bb[j] = (colOut + j < N) ? bias[colOut + j] : 0.0f;
#pragma unroll
    for (int i = 0; i < 8; ++i) {
        int rowL = ty * 8 + i;
        int row = rowBase + rowL;
        float rs = 1.0f;
        if (row < M) { float di = dinv[row]; rs = di * di + colsumS[row]; }
#pragma unroll
        for (int j = 0; j < 4; ++j)
            if (colOut + j < N) sOut[rowL][colOut + j] = acc[i][j] + rs * bb[j];
    }
    __syncthreads();
    if (tid < 128) {
        int row = rowBase + tid;
        if (row < M) {
            float mx = -INFINITY;
            for (int c = 0; c < N; ++c) mx = fmaxf(mx, sOut[tid][c]);
            float sm = 0.f;
            for (int c = 0; c < N; ++c) sm += expf(sOut[tid][c] - mx);
            float lg = mx + logf(sm);
            float* op = out + (size_t)row * N;
            for (int c = 0; c < N; ++c) op[c] = sOut[tid][c] - lg;
        }
    }
}

// ---------------- fp32 aggregation (layer 1) + colsumS (NO stats atomics) ----------------

__global__ __launch_bounds__(256) void aggregate128_par(
        const float* __restrict__ h, const float* __restrict__ dinv,
        const float* __restrict__ nodeWf,
        const int* __restrict__ start, const int* __restrict__ indeg,
        const int* __restrict__ ssrc, float* __restrict__ out,
        float* __restrict__ colsumS, int n, int E) {
    __shared__ int   sIdx[256];
    __shared__ float sW[256];
    __shared__ float red[8][132];
    __shared__ float wpart[4];
    int node = blockIdx.x;
    int tid = threadIdx.x;
    int c4 = (tid & 31) * 4;
    int slot = tid >> 5;
    float di = dinv[node];
    int s0 = start[node];
    int len = indeg[node];
    if (s0 < 0) s0 = 0;
    if (len < 0) len = 0;
    if (s0 + len > E) len = (E - s0 > 0) ? (E - s0) : 0;

    float4 acc = {0.f, 0.f, 0.f, 0.f};
    float wacc = 0.f;
    for (int chunk = 0; chunk < len; chunk += 256) {
        int m = len - chunk; if (m > 256) m = 256;
        if (tid < m) {
            int s = ssrc[s0 + chunk + tid];
            float w;
            if ((unsigned)s >= (unsigned)n) { s = node; w = 0.f; }
            else w = nodeWf[(size_t)s * 4] * di;
            sIdx[tid] = s; sW[tid] = w; wacc += w;
        }
        __syncthreads();
        int j = slot;
        for (; j + 8 < m; j += 16) {
            int sa = sIdx[j], sb = sIdx[j + 8];
            float wa = sW[j], wb = sW[j + 8];
            float4 va = *(const float4*)(h + (size_t)sa * 128 + c4);
            float4 vb = *(const float4*)(h + (size_t)sb * 128 + c4);
            acc.x = fmaf(va.x, wa, acc.x); acc.y = fmaf(va.y, wa, acc.y);
            acc.z = fmaf(va.z, wa, acc.z); acc.w = fmaf(va.w, wa, acc.w);
            acc.x = fmaf(vb.x, wb, acc.x); acc.y = fmaf(vb.y, wb, acc.y);
            acc.z = fmaf(vb.z, wb, acc.z); acc.w = fmaf(vb.w, wb, acc.w);
        }
        if (j < m) {
            int sa = sIdx[j];
            float wa = sW[j];
            float4 va = *(const float4*)(h + (size_t)sa * 128 + c4);
            acc.x = fmaf(va.x, wa, acc.x); acc.y = fmaf(va.y, wa, acc.y);
            acc.z = fmaf(va.z, wa, acc.z); acc.w = fmaf(va.w, wa, acc.w);
        }
        __syncthreads();
    }
#pragma unroll
    for (int o = 1; o < 64; o <<= 1) wacc += __shfl_xor(wacc, o);
    if ((tid & 63) == 0) wpart[tid >> 6] = wacc;
    *(float4*)&red[slot][c4] = acc;
    __syncthreads();
    if (tid == 0) colsumS[node] = wpart[0] + wpart[1] + wpart[2] + wpart[3];
    if (tid < 128) {
        int c = tid;
        float r = h[(size_t)node * 128 + c] * di * di;    // self loop
#pragma unroll
        for (int s = 0; s < 8; ++s) r += red[s][c];
        out[(size_t)node * 128 + c] = r;
    }
}

// ---------------- 4-bit-packed aggregation (layers 2,3): one WAVE per node ----------------
// qp: n x 64 bytes (2 codes/byte). 16 slots x 4 lanes x uint4 (one 64B row per slot),
// unroll x2 -> 32 rows in flight per wave. Shuffle reductions only.

__device__ __forceinline__ void unpack32(float* acc, uint4 v, float w) {
    unsigned u[4] = {v.x, v.y, v.z, v.w};
#pragma unroll
    for (int i = 0; i < 4; ++i)
#pragma unroll
        for (int k = 0; k < 8; ++k)
            acc[i * 8 + k] = fmaf((float)((u[i] >> (4 * k)) & 15u), w, acc[i * 8 + k]);
}

__global__ __launch_bounds__(256) void aggregate_q4_wave(
        const unsigned char* __restrict__ qp, const float* __restrict__ dinv,
        const float* __restrict__ gscale, const float* __restrict__ nodeWf, int gsel,
        const int* __restrict__ start, const int* __restrict__ indeg,
        const int* __restrict__ ssrc, float* __restrict__ out, int n, int E) {
    int node = blockIdx.x * 4 + (threadIdx.x >> 6);
    if (node >= n) return;
    int lane = threadIdx.x & 63;
    int slot = lane >> 2;      // 0..15
    int sl   = lane & 3;       // covers bytes sl*16..sl*16+15 -> channels sl*32..sl*32+31
    float di = dinv[node];
    int s0 = start[node];
    int len = indeg[node];
    if (s0 < 0) s0 = 0;
    if (len < 0) len = 0;
    if (s0 + len > E) len = (E - s0 > 0) ? (E - s0) : 0;

    float acc[32] = {};
    int j = slot;
    for (; j + 16 < len; j += 32) {
        int sa = ssrc[s0 + j];
        int sb = ssrc[s0 + j + 16];
        float wa, wb;
        if ((unsigned)sa >= (unsigned)n) { sa = node; wa = 0.f; }
        else wa = nodeWf[(size_t)sa * 4 + gsel] * di;
        if ((unsigned)sb >= (unsigned)n) { sb = node; wb = 0.f; }
        else wb = nodeWf[(size_t)sb * 4 + gsel] * di;
        uint4 va = *(const uint4*)(qp + (size_t)sa * 64 + sl * 16);
        uint4 vb = *(const uint4*)(qp + (size_t)sb * 64 + sl * 16);
        unpack32(acc, va, wa);
        unpack32(acc, vb, wb);
    }
    if (j < len) {
        int sa = ssrc[s0 + j];
        float wa;
        if ((unsigned)sa >= (unsigned)n) { sa = node; wa = 0.f; }
        else wa = nodeWf[(size_t)sa * 4 + gsel] * di;
        uint4 va = *(const uint4*)(qp + (size_t)sa * 64 + sl * 16);
        unpack32(acc, va, wa);
    }
    // reduce across 16 slots (lane bits 2..5)
#pragma unroll
    for (int o = 4; o < 64; o <<= 1) {
#pragma unroll
        for (int k = 0; k < 32; ++k) acc[k] += __shfl_xor(acc[k], o);
    }
    if (slot == 0) {
        uint4 vs = *(const uint4*)(qp + (size_t)node * 64 + sl * 16);
        unpack32(acc, vs, gscale[node] * di * di);   // self loop
        float* op = out + (size_t)node * 128 + sl * 32;
#pragma unroll
        for (int k = 0; k < 8; ++k)
            *(float4*)(op + k * 4) = *(float4*)&acc[k * 4];
    }
}

// ---------------- BatchNorm ----------------

__global__ void bn_stats(const float* __restrict__ x, int n,
                         float* __restrict__ sums, float* __restrict__ sumsq) {
    int c = threadIdx.x;   // 128
    float s = 0.f, s2 = 0.f;
    for (int r = blockIdx.x; r < n; r += gridDim.x) {
        float v = x[(size_t)r * 128 + c];
        s += v; s2 += v * v;
    }
    atomicAdd(&sums[c], s);
    atomicAdd(&sumsq[c], s2);
}

__global__ void bn_reduce(float* __restrict__ statsP) {
    int t = threadIdx.x;   // 256
    float s = 0.f;
    for (int k = 0; k < 64; ++k) s += statsP[k * 256 + t];
    __syncthreads();
    statsP[t] = s;
}

// BN finalize + affine + ReLU + 4-bit fake-quant -> packed nibbles (2 channels/thread)
__global__ void bn_apply_quant_u4(const float* __restrict__ x,
                                  const float* __restrict__ sums,
                                  const float* __restrict__ sumsq,
                                  const float* __restrict__ g, const float* __restrict__ b,
                                  const float* __restrict__ gs,
                                  unsigned char* __restrict__ out, int n) {
    int idx = blockIdx.x * blockDim.x + threadIdx.x;
    if (idx >= n * 64) return;
    int k = idx & 63;
    int r = idx >> 6;
    int c0 = k * 2;
    float2 xv = *(const float2*)(x + (size_t)r * 128 + c0);
    float2 sm = *(const float2*)(sums + c0);
    float2 sq = *(const float2*)(sumsq + c0);
    float2 gg = *(const float2*)(g + c0);
    float2 bb = *(const float2*)(b + c0);
    float gsr = gs[r];
    float inv_n = 1.0f / (float)n;

    float m0 = sm.x * inv_n;
    float a0 = gg.x * (1.0f / sqrtf(sq.x * inv_n - m0 * m0 + 1e-5f));
    float v0 = a0 * xv.x + (bb.x - m0 * a0);
    v0 = fmaxf(v0, 0.0f);
    float q0 = rintf(fminf(fmaxf(v0 / gsr, 0.0f), 15.0f));

    float m1 = sm.y * inv_n;
    float a1 = gg.y * (1.0f / sqrtf(sq.y * inv_n - m1 * m1 + 1e-5f));
    float v1 = a1 * xv.y + (bb.y - m1 * a1);
    v1 = fmaxf(v1, 0.0f);
    float q1 = rintf(fminf(fmaxf(v1 / gsr, 0.0f), 15.0f));

    out[(size_t)r * 64 + k] = (unsigned char)((int)q0 | ((int)q1 << 4));
}

// ---------------- launch ----------------

extern "C" void kernel_launch(void* const* d_in, const int* in_sizes, int n_in,
                              void* d_out, int out_size, void* d_ws, size_t ws_size,
                              hipStream_t stream) {
    float*       xbuf = (float*)d_in[0];          // reused as scratch after layer-1 GEMM
    const int*   ei   = (const int*)d_in[1];
    const float* W1   = (const float*)d_in[2];
    const float* b1   = (const float*)d_in[3];
    const float* a1   = (const float*)d_in[4];
    const float* W2   = (const float*)d_in[5];
    const float* b2   = (const float*)d_in[6];
    const float* a2   = (const float*)d_in[7];
    const float* g2   = (const float*)d_in[8];
    const float* W3   = (const float*)d_in[9];
    const float* b3   = (const float*)d_in[10];
    const float* a3   = (const float*)d_in[11];
    const float* g3   = (const float*)d_in[12];
    const float* bn1g = (const float*)d_in[13];
    const float* bn1b = (const float*)d_in[14];
    const float* bn2g = (const float*)d_in[15];
    const float* bn2b = (const float*)d_in[16];

    const int n = in_sizes[0] / 128;      // 50000
    const int E = in_sizes[1] / 2;        // 800000
    const int C = in_sizes[9] / 128;      // 40
    const int* src = ei;
    const int* dst = ei + E;

    // ---- workspace layout: zeroed region FIRST ----
    char* wsp = (char*)d_ws;
    size_t off = 0;
    auto take = [&](size_t bytes) -> void* {
        void* p = wsp + off;
        off += (bytes + 255) & ~(size_t)255;
        return p;
    };
    int*   indeg   = (int*)take((size_t)n * 4);
    int*   counter = (int*)take(4);
    float* stats1  = (float*)take(256 * 4);          // layer-1: sums | sumsq
    float* stats2  = (float*)take(64 * 256 * 4);     // layer-2: 64 partial copies
    size_t zeroBytes = off;
    int*   startA  = (int*)take((size_t)n * 4);
    int*   cursor  = (int*)take((size_t)n * 4);
    float* dinv    = (float*)take((size_t)n * 4);
    float* colsumS = (float*)take((size_t)n * 4);
    float4* nodeW  = (float4*)take((size_t)n * 16);
    int*   ssrc    = (int*)take((size_t)E * 4);
    float* w1q     = (float*)take(128 * 128 * 4);
    float* w2q     = (float*)take(128 * 128 * 4);
    float* w3q     = (float*)take((size_t)128 * C * 4);
    unsigned char* qbuf = (unsigned char*)take((size_t)n * 64);
    float* hbuf    = (float*)take((size_t)n * 128 * 4);

    float* outF  = (float*)d_out;
    const float* nodeWf = (const float*)nodeW;

    // ---- setup ----
    hipMemsetAsync(d_ws, 0, zeroBytes, stream);
    count_indeg<<<(E + 255) / 256, 256, 0, stream>>>(dst, E, indeg);
    const int nW = 128 * 128 + 128 * 128 + 128 * C;
    int setupN = (n > nW) ? n : nW;
    setup_misc<<<(setupN + 255) / 256, 256, 0, stream>>>(
        indeg, dinv, startA, cursor, counter, g2, g3, nodeW, n,
        W1, a1, W2, a2, W3, a3, w1q, w2q, w3q, 128 * 128, 128 * 128, 128 * C);
    fill_csr_min<<<(E + 255) / 256, 256, 0, stream>>>(src, dst, E, cursor, ssrc, n);

    const int gElem64 = (n * 64 + 255) / 256;
    const int gWave = (n + 3) / 4;
    const int gRow128 = (n + 127) / 128;

    // ---- layer 1 ----
    gemm128_bias<<<gRow128, 256, 0, stream>>>(xbuf, w1q, b1, nullptr, nullptr,
                                              hbuf, nullptr, n, 128);
    aggregate128_par<<<n, 256, 0, stream>>>(hbuf, dinv, nodeWf, startA, indeg, ssrc,
                                            xbuf, colsumS, n, E);
    bn_stats<<<512, 128, 0, stream>>>(xbuf, n, stats1, stats1 + 128);
    bn_apply_quant_u4<<<gElem64, 256, 0, stream>>>(xbuf, stats1, stats1 + 128,
                                                   bn1g, bn1b, g2, qbuf, n);

    // ---- layer 2: aggregate(q)*W + rowsum*b (stats fused into GEMM) ----
    aggregate_q4_wave<<<gWave, 256, 0, stream>>>(qbuf, dinv, g2, nodeWf, 1, startA, indeg,
                                                 ssrc, hbuf, n, E);
    gemm128_bias<<<gRow128, 256, 0, stream>>>(hbuf, w2q, b2, dinv, colsumS,
                                              xbuf, stats2, n, 128);
    bn_reduce<<<1, 256, 0, stream>>>(stats2);
    bn_apply_quant_u4<<<gElem64, 256, 0, stream>>>(xbuf, stats2, stats2 + 128,
                                                   bn2g, bn2b, g3, qbuf, n);

    // ---- layer 3: aggregate(q)*W3 + rowsum*b3, softmax fused ----
    aggregate_q4_wave<<<gWave, 256, 0, stream>>>(qbuf, dinv, g3, nodeWf, 2, startA, indeg,
                                                 ssrc, hbuf, n, E);
    gemm40_softmax<<<gRow128, 256, 0, stream>>>(hbuf, w3q, b3, dinv, colsumS,
                                                outF, n, C, 128);
}

// Round 13
// 502.759 us; speedup vs baseline: 1.1316x; 1.1316x over previous
//
#include <hip/hip_runtime.h>
#include <hip/hip_bf16.h>
#include <math.h>

// ---------------- graph structure ----------------

__global__ void count_indeg(const int* __restrict__ dst, int e, int* __restrict__ indeg) {
    int i = blockIdx.x * blockDim.x + threadIdx.x;
    if (i < e) atomicAdd(&indeg[dst[i]], 1);
}

// fused setup: dinv + ranges + nodeW table (i < n)  |  weight fake-quant (i < nW)
__global__ void setup_misc(const int* __restrict__ indeg, float* __restrict__ dinv,
                           int* __restrict__ start, int* __restrict__ cursor,
                           int* __restrict__ counter,
                           const float* __restrict__ g2, const float* __restrict__ g3,
                           float4* __restrict__ nodeW, int n,
                           const float* __restrict__ W1, const float* __restrict__ a1,
                           const float* __restrict__ W2, const float* __restrict__ a2,
                           const float* __restrict__ W3, const float* __restrict__ a3,
                           float* __restrict__ w1q, float* __restrict__ w2q,
                           float* __restrict__ w3q, int n1, int n2, int n3) {
    int i = blockIdx.x * blockDim.x + threadIdx.x;
    if (i < n) {
        int d = indeg[i];
        float ds = 1.0f / sqrtf((float)(d + 1));
        dinv[i] = ds;
        nodeW[i] = make_float4(ds, ds * g2[i], ds * g3[i], 0.0f);
        int s = atomicAdd(counter, d);
        start[i] = s;
        cursor[i] = s;
    }
    const float* w; const float* a; float* o; int k;
    if (i < n1) { w = W1; a = a1; o = w1q; k = i; }
    else if (i < n1 + n2) { w = W2; a = a2; o = w2q; k = i - n1; }
    else if (i < n1 + n2 + n3) { w = W3; a = a3; o = w3q; k = i - n1 - n2; }
    else return;
    float s = a[0];
    float v = w[k] / s;
    v = fminf(fmaxf(v, -8.0f), 7.0f);
    o[k] = rintf(v) * s;   // round-half-even, matches jnp.round
}

// minimal CSR fill: one atomic + one 4B store per edge
__global__ void fill_csr_min(const int* __restrict__ src, const int* __restrict__ dst,
                             int e, int* __restrict__ cursor, int* __restrict__ ssrc, int n) {
    int i = blockIdx.x * blockDim.x + threadIdx.x;
    if (i >= e) return;
    int s = src[i];
    int p = atomicAdd(&cursor[dst[i]], 1);
    if (p >= 0 && p < e) ssrc[p] = ((unsigned)s < (unsigned)n) ? s : -1;
}

// ---------------- GEMM 128-col + optional fused BN-stats partials ----------------

__global__ __launch_bounds__(256) void gemm128_bias(
        const float* __restrict__ A, const float* __restrict__ B,
        const float* __restrict__ bias,
        const float* __restrict__ dinv, const float* __restrict__ colsumS,
        float* __restrict__ C, float* __restrict__ statsP, int M, int K) {
    __shared__ float sA[16][132];
    __shared__ float sB[16][132];
    int tid = threadIdx.x;
    int rowBase = blockIdx.x * 128;
    int tx = tid & 15;
    int ty = tid >> 4;
    float acc[8][8] = {};

    int aRow = tid >> 1;
    int aK   = (tid & 1) * 8;
    int bK   = tid >> 4;
    int bCol = (tid & 15) * 8;

    for (int k0 = 0; k0 < K; k0 += 16) {
        int gRow = rowBase + aRow;
        if (gRow >= M) gRow = M - 1;
        const float* ap = A + (size_t)gRow * K + k0 + aK;
        float4 a0 = *(const float4*)ap;
        float4 a1 = *(const float4*)(ap + 4);
        sA[aK + 0][aRow] = a0.x;
        sA[aK + 1][aRow] = a0.y;
        sA[aK + 2][aRow] = a0.z;
        sA[aK + 3][aRow] = a0.w;
        sA[aK + 4][aRow] = a1.x;
        sA[aK + 5][aRow] = a1.y;
        sA[aK + 6][aRow] = a1.z;
        sA[aK + 7][aRow] = a1.w;
        const float* bp = B + (size_t)(k0 + bK) * 128 + bCol;
        *(float4*)&sB[bK][bCol]     = *(const float4*)bp;
        *(float4*)&sB[bK][bCol + 4] = *(const float4*)(bp + 4);
        __syncthreads();

#pragma unroll
        for (int kk = 0; kk < 16; ++kk) {
            float4 av0 = *(const float4*)&sA[kk][ty * 8];
            float4 av1 = *(const float4*)&sA[kk][ty * 8 + 4];
            float4 bv0 = *(const float4*)&sB[kk][tx * 4];
            float4 bv1 = *(const float4*)&sB[kk][64 + tx * 4];
            float a[8] = {av0.x, av0.y, av0.z, av0.w, av1.x, av1.y, av1.z, av1.w};
            float b[8] = {bv0.x, bv0.y, bv0.z, bv0.w, bv1.x, bv1.y, bv1.z, bv1.w};
#pragma unroll
            for (int i = 0; i < 8; ++i)
#pragma unroll
                for (int j = 0; j < 8; ++j)
                    acc[i][j] = fmaf(a[i], b[j], acc[i][j]);
        }
        __syncthreads();
    }

    int c0 = tx * 4, c1 = 64 + tx * 4;
    float bb[8];
#pragma unroll
    for (int j = 0; j < 4; ++j) { bb[j] = bias[c0 + j]; bb[4 + j] = bias[c1 + j]; }
    float s1[8] = {}, s2[8] = {};
#pragma unroll
    for (int i = 0; i < 8; ++i) {
        int row = rowBase + ty * 8 + i;
        if (row >= M) continue;
        float rs = 1.0f;
        if (dinv) { float di = dinv[row]; rs = di * di + colsumS[row]; }
        float v[8];
#pragma unroll
        for (int j = 0; j < 8; ++j) {
            v[j] = acc[i][j] + rs * bb[j];
            s1[j] += v[j];
            s2[j] += v[j] * v[j];
        }
        *(float4*)&C[(size_t)row * 128 + c0] = *(float4*)&v[0];
        *(float4*)&C[(size_t)row * 128 + c1] = *(float4*)&v[4];
    }
    if (statsP) {
        float* sp = statsP + (blockIdx.x & 63) * 256;
#pragma unroll
        for (int j = 0; j < 4; ++j) { sA[ty][c0 + j] = s1[j]; sA[ty][c1 + j] = s1[4 + j]; }
        __syncthreads();
        if (tid < 128) {
            float t = 0.f;
#pragma unroll
            for (int k = 0; k < 16; ++k) t += sA[k][tid];
            atomicAdd(&sp[tid], t);
        }
        __syncthreads();
#pragma unroll
        for (int j = 0; j < 4; ++j) { sA[ty][c0 + j] = s2[j]; sA[ty][c1 + j] = s2[4 + j]; }
        __syncthreads();
        if (tid < 128) {
            float t = 0.f;
#pragma unroll
            for (int k = 0; k < 16; ++k) t += sA[k][tid];
            atomicAdd(&sp[128 + tid], t);
        }
    }
}

// ---------------- layer-3 GEMM (N<=64) + fused log_softmax ----------------

__global__ __launch_bounds__(256) void gemm40_softmax(
        const float* __restrict__ A, const float* __restrict__ B,
        const float* __restrict__ bias,
        const float* __restrict__ dinv, const float* __restrict__ colsumS,
        float* __restrict__ out, int M, int N, int K) {
    __shared__ float sA[16][132];
    __shared__ float sB[16][68];
    __shared__ float sOut[128][41];
    int tid = threadIdx.x;
    int rowBase = blockIdx.x * 128;
    int tx = tid & 15;
    int ty = tid >> 4;
    float acc[8][4] = {};

    int aRow = tid >> 1;
    int aK   = (tid & 1) * 8;
    int bK   = tid >> 4;
    int bCol = (tid & 15) * 4;

    for (int k0 = 0; k0 < K; k0 += 16) {
        int gRow = rowBase + aRow;
        if (gRow >= M) gRow = M - 1;
        const float* ap = A + (size_t)gRow * K + k0 + aK;
        float4 a0 = *(const float4*)ap;
        float4 a1 = *(const float4*)(ap + 4);
        sA[aK + 0][aRow] = a0.x;
        sA[aK + 1][aRow] = a0.y;
        sA[aK + 2][aRow] = a0.z;
        sA[aK + 3][aRow] = a0.w;
        sA[aK + 4][aRow] = a1.x;
        sA[aK + 5][aRow] = a1.y;
        sA[aK + 6][aRow] = a1.z;
        sA[aK + 7][aRow] = a1.w;
#pragma unroll
        for (int j = 0; j < 4; ++j) {
            int col = bCol + j;
            sB[bK][col] = (col < N) ? B[(size_t)(k0 + bK) * N + col] : 0.0f;
        }
        __syncthreads();
#pragma unroll
        for (int kk = 0; kk < 16; ++kk) {
            float4 av0 = *(const float4*)&sA[kk][ty * 8];
            float4 av1 = *(const float4*)&sA[kk][ty * 8 + 4];
            float4 bv  = *(const float4*)&sB[kk][tx * 4];
            float a[8] = {av0.x, av0.y, av0.z, av0.w, av1.x, av1.y, av1.z, av1.w};
            float b[4] = {bv.x, bv.y, bv.z, bv.w};
#pragma unroll
            for (int i = 0; i < 8; ++i)
#pragma unroll
                for (int j = 0; j < 4; ++j)
                    acc[i][j] = fmaf(a[i], b[j], acc[i][j]);
        }
        __syncthreads();
    }

    int colOut = tx * 4;
    float bb[4];
#pragma unroll
    for (int j = 0; j < 4; ++j) bb[j] = (colOut + j < N) ? bias[colOut + j] : 0.0f;
#pragma unroll
    for (int i = 0; i < 8; ++i) {
        int rowL = ty * 8 + i;
        int row = rowBase + rowL;
        float rs = 1.0f;
        if (row < M) { float di = dinv[row]; rs = di * di + colsumS[row]; }
#pragma unroll
        for (int j = 0; j < 4; ++j)
            if (colOut + j < N) sOut[rowL][colOut + j] = acc[i][j] + rs * bb[j];
    }
    __syncthreads();
    if (tid < 128) {
        int row = rowBase + tid;
        if (row < M) {
            float mx = -INFINITY;
            for (int c = 0; c < N; ++c) mx = fmaxf(mx, sOut[tid][c]);
            float sm = 0.f;
            for (int c = 0; c < N; ++c) sm += expf(sOut[tid][c] - mx);
            float lg = mx + logf(sm);
            float* op = out + (size_t)row * N;
            for (int c = 0; c < N; ++c) op[c] = sOut[tid][c] - lg;
        }
    }
}

// ---------------- fp32 aggregation (layer 1) + colsumS (NO stats atomics) ----------------

__global__ __launch_bounds__(256) void aggregate128_par(
        const float* __restrict__ h, const float* __restrict__ dinv,
        const float* __restrict__ nodeWf,
        const int* __restrict__ start, const int* __restrict__ indeg,
        const int* __restrict__ ssrc, float* __restrict__ out,
        float* __restrict__ colsumS, int n, int E) {
    __shared__ int   sIdx[256];
    __shared__ float sW[256];
    __shared__ float red[8][132];
    __shared__ float wpart[4];
    int node = blockIdx.x;
    int tid = threadIdx.x;
    int c4 = (tid & 31) * 4;
    int slot = tid >> 5;
    float di = dinv[node];
    int s0 = start[node];
    int len = indeg[node];
    if (s0 < 0) s0 = 0;
    if (len < 0) len = 0;
    if (s0 + len > E) len = (E - s0 > 0) ? (E - s0) : 0;

    float4 acc = {0.f, 0.f, 0.f, 0.f};
    float wacc = 0.f;
    for (int chunk = 0; chunk < len; chunk += 256) {
        int m = len - chunk; if (m > 256) m = 256;
        if (tid < m) {
            int s = ssrc[s0 + chunk + tid];
            float w;
            if ((unsigned)s >= (unsigned)n) { s = node; w = 0.f; }
            else w = nodeWf[(size_t)s * 4] * di;
            sIdx[tid] = s; sW[tid] = w; wacc += w;
        }
        __syncthreads();
        int j = slot;
        for (; j + 8 < m; j += 16) {
            int sa = sIdx[j], sb = sIdx[j + 8];
            float wa = sW[j], wb = sW[j + 8];
            float4 va = *(const float4*)(h + (size_t)sa * 128 + c4);
            float4 vb = *(const float4*)(h + (size_t)sb * 128 + c4);
            acc.x = fmaf(va.x, wa, acc.x); acc.y = fmaf(va.y, wa, acc.y);
            acc.z = fmaf(va.z, wa, acc.z); acc.w = fmaf(va.w, wa, acc.w);
            acc.x = fmaf(vb.x, wb, acc.x); acc.y = fmaf(vb.y, wb, acc.y);
            acc.z = fmaf(vb.z, wb, acc.z); acc.w = fmaf(vb.w, wb, acc.w);
        }
        if (j < m) {
            int sa = sIdx[j];
            float wa = sW[j];
            float4 va = *(const float4*)(h + (size_t)sa * 128 + c4);
            acc.x = fmaf(va.x, wa, acc.x); acc.y = fmaf(va.y, wa, acc.y);
            acc.z = fmaf(va.z, wa, acc.z); acc.w = fmaf(va.w, wa, acc.w);
        }
        __syncthreads();
    }
#pragma unroll
    for (int o = 1; o < 64; o <<= 1) wacc += __shfl_xor(wacc, o);
    if ((tid & 63) == 0) wpart[tid >> 6] = wacc;
    *(float4*)&red[slot][c4] = acc;
    __syncthreads();
    if (tid == 0) colsumS[node] = wpart[0] + wpart[1] + wpart[2] + wpart[3];
    if (tid < 128) {
        int c = tid;
        float r = h[(size_t)node * 128 + c] * di * di;    // self loop
#pragma unroll
        for (int s = 0; s < 8; ++s) r += red[s][c];
        out[(size_t)node * 128 + c] = r;
    }
}

// ---------------- u8 aggregation (layers 2,3): one WAVE per node ----------------
// 8 slots x 8 lanes x uint4 (one 128B row per slot), unroll x2. Shuffle reductions only.

__device__ __forceinline__ void unpack_fma(float* acc, uint4 v, float w) {
    acc[0]  = fmaf((float)(v.x & 255), w, acc[0]);
    acc[1]  = fmaf((float)((v.x >> 8) & 255), w, acc[1]);
    acc[2]  = fmaf((float)((v.x >> 16) & 255), w, acc[2]);
    acc[3]  = fmaf((float)(v.x >> 24), w, acc[3]);
    acc[4]  = fmaf((float)(v.y & 255), w, acc[4]);
    acc[5]  = fmaf((float)((v.y >> 8) & 255), w, acc[5]);
    acc[6]  = fmaf((float)((v.y >> 16) & 255), w, acc[6]);
    acc[7]  = fmaf((float)(v.y >> 24), w, acc[7]);
    acc[8]  = fmaf((float)(v.z & 255), w, acc[8]);
    acc[9]  = fmaf((float)((v.z >> 8) & 255), w, acc[9]);
    acc[10] = fmaf((float)((v.z >> 16) & 255), w, acc[10]);
    acc[11] = fmaf((float)(v.z >> 24), w, acc[11]);
    acc[12] = fmaf((float)(v.w & 255), w, acc[12]);
    acc[13] = fmaf((float)((v.w >> 8) & 255), w, acc[13]);
    acc[14] = fmaf((float)((v.w >> 16) & 255), w, acc[14]);
    acc[15] = fmaf((float)(v.w >> 24), w, acc[15]);
}

__global__ __launch_bounds__(256) void aggregate_q8_wave(
        const unsigned char* __restrict__ q, const float* __restrict__ dinv,
        const float* __restrict__ gscale, const float* __restrict__ nodeWf, int gsel,
        const int* __restrict__ start, const int* __restrict__ indeg,
        const int* __restrict__ ssrc, float* __restrict__ out, int n, int E) {
    int node = blockIdx.x * 4 + (threadIdx.x >> 6);
    if (node >= n) return;
    int lane = threadIdx.x & 63;
    int slot = lane >> 3;      // 0..7
    int sl   = lane & 7;       // covers bytes sl*16..sl*16+15
    float di = dinv[node];
    int s0 = start[node];
    int len = indeg[node];
    if (s0 < 0) s0 = 0;
    if (len < 0) len = 0;
    if (s0 + len > E) len = (E - s0 > 0) ? (E - s0) : 0;

    float acc[16] = {};
    int j = slot;
    for (; j + 8 < len; j += 16) {
        int sa = ssrc[s0 + j];
        int sb = ssrc[s0 + j + 8];
        float wa, wb;
        if ((unsigned)sa >= (unsigned)n) { sa = node; wa = 0.f; }
        else wa = nodeWf[(size_t)sa * 4 + gsel] * di;
        if ((unsigned)sb >= (unsigned)n) { sb = node; wb = 0.f; }
        else wb = nodeWf[(size_t)sb * 4 + gsel] * di;
        uint4 va = *(const uint4*)(q + (size_t)sa * 128 + sl * 16);
        uint4 vb = *(const uint4*)(q + (size_t)sb * 128 + sl * 16);
        unpack_fma(acc, va, wa);
        unpack_fma(acc, vb, wb);
    }
    if (j < len) {
        int sa = ssrc[s0 + j];
        float wa;
        if ((unsigned)sa >= (unsigned)n) { sa = node; wa = 0.f; }
        else wa = nodeWf[(size_t)sa * 4 + gsel] * di;
        uint4 va = *(const uint4*)(q + (size_t)sa * 128 + sl * 16);
        unpack_fma(acc, va, wa);
    }
#pragma unroll
    for (int o = 8; o < 64; o <<= 1) {
#pragma unroll
        for (int k = 0; k < 16; ++k) acc[k] += __shfl_xor(acc[k], o);
    }
    if (slot == 0) {
        uint4 vs = *(const uint4*)(q + (size_t)node * 128 + sl * 16);
        unpack_fma(acc, vs, gscale[node] * di * di);   // self loop
        float* op = out + (size_t)node * 128 + sl * 16;
        *(float4*)(op + 0)  = *(float4*)&acc[0];
        *(float4*)(op + 4)  = *(float4*)&acc[4];
        *(float4*)(op + 8)  = *(float4*)&acc[8];
        *(float4*)(op + 12) = *(float4*)&acc[12];
    }
}

// ---------------- BatchNorm ----------------

__global__ void bn_stats(const float* __restrict__ x, int n,
                         float* __restrict__ sums, float* __restrict__ sumsq) {
    int c = threadIdx.x;   // 128
    float s = 0.f, s2 = 0.f;
    for (int r = blockIdx.x; r < n; r += gridDim.x) {
        float v = x[(size_t)r * 128 + c];
        s += v; s2 += v * v;
    }
    atomicAdd(&sums[c], s);
    atomicAdd(&sumsq[c], s2);
}

__global__ void bn_reduce(float* __restrict__ statsP) {
    int t = threadIdx.x;   // 256
    float s = 0.f;
    for (int k = 0; k < 64; ++k) s += statsP[k * 256 + t];
    __syncthreads();
    statsP[t] = s;
}

// BN finalize (per-thread) + affine + ReLU + 4-bit fake-quant -> u8 code (0..15)
__global__ void bn_apply_quant_u8(const float* __restrict__ x,
                                  const float* __restrict__ sums,
                                  const float* __restrict__ sumsq,
                                  const float* __restrict__ g, const float* __restrict__ b,
                                  const float* __restrict__ gs,
                                  unsigned char* __restrict__ out, int n) {
    int idx = blockIdx.x * blockDim.x + threadIdx.x;
    if (idx >= n * 128) return;
    int c = idx & 127;
    int r = idx >> 7;
    float m  = sums[c] / (float)n;
    float vr = sumsq[c] / (float)n - m * m;
    float a  = g[c] * (1.0f / sqrtf(vr + 1e-5f));
    float bp = b[c] - m * a;
    float v = a * x[idx] + bp;
    v = fmaxf(v, 0.0f);
    float qv = fminf(fmaxf(v / gs[r], 0.0f), 15.0f);
    out[idx] = (unsigned char)rintf(qv);   // round-half-even
}

// ---------------- launch ----------------

extern "C" void kernel_launch(void* const* d_in, const int* in_sizes, int n_in,
                              void* d_out, int out_size, void* d_ws, size_t ws_size,
                              hipStream_t stream) {
    float*       xbuf = (float*)d_in[0];          // reused as scratch after layer-1 GEMM
    const int*   ei   = (const int*)d_in[1];
    const float* W1   = (const float*)d_in[2];
    const float* b1   = (const float*)d_in[3];
    const float* a1   = (const float*)d_in[4];
    const float* W2   = (const float*)d_in[5];
    const float* b2   = (const float*)d_in[6];
    const float* a2   = (const float*)d_in[7];
    const float* g2   = (const float*)d_in[8];
    const float* W3   = (const float*)d_in[9];
    const float* b3   = (const float*)d_in[10];
    const float* a3   = (const float*)d_in[11];
    const float* g3   = (const float*)d_in[12];
    const float* bn1g = (const float*)d_in[13];
    const float* bn1b = (const float*)d_in[14];
    const float* bn2g = (const float*)d_in[15];
    const float* bn2b = (const float*)d_in[16];

    const int n = in_sizes[0] / 128;      // 50000
    const int E = in_sizes[1] / 2;        // 800000
    const int C = in_sizes[9] / 128;      // 40
    const int* src = ei;
    const int* dst = ei + E;

    // ---- workspace layout: zeroed region FIRST ----
    char* wsp = (char*)d_ws;
    size_t off = 0;
    auto take = [&](size_t bytes) -> void* {
        void* p = wsp + off;
        off += (bytes + 255) & ~(size_t)255;
        return p;
    };
    int*   indeg   = (int*)take((size_t)n * 4);
    int*   counter = (int*)take(4);
    float* stats1  = (float*)take(256 * 4);          // layer-1: sums | sumsq
    float* stats2  = (float*)take(64 * 256 * 4);     // layer-2: 64 partial copies
    size_t zeroBytes = off;
    int*   startA  = (int*)take((size_t)n * 4);
    int*   cursor  = (int*)take((size_t)n * 4);
    float* dinv    = (float*)take((size_t)n * 4);
    float* colsumS = (float*)take((size_t)n * 4);
    float4* nodeW  = (float4*)take((size_t)n * 16);
    int*   ssrc    = (int*)take((size_t)E * 4);
    float* w1q     = (float*)take(128 * 128 * 4);
    float* w2q     = (float*)take(128 * 128 * 4);
    float* w3q     = (float*)take((size_t)128 * C * 4);
    unsigned char* qbuf = (unsigned char*)take((size_t)n * 128);
    float* hbuf    = (float*)take((size_t)n * 128 * 4);

    float* outF  = (float*)d_out;
    const float* nodeWf = (const float*)nodeW;

    // ---- setup ----
    hipMemsetAsync(d_ws, 0, zeroBytes, stream);
    count_indeg<<<(E + 255) / 256, 256, 0, stream>>>(dst, E, indeg);
    const int nW = 128 * 128 + 128 * 128 + 128 * C;
    int setupN = (n > nW) ? n : nW;
    setup_misc<<<(setupN + 255) / 256, 256, 0, stream>>>(
        indeg, dinv, startA, cursor, counter, g2, g3, nodeW, n,
        W1, a1, W2, a2, W3, a3, w1q, w2q, w3q, 128 * 128, 128 * 128, 128 * C);
    fill_csr_min<<<(E + 255) / 256, 256, 0, stream>>>(src, dst, E, cursor, ssrc, n);

    const int gElem128 = (n * 128 + 255) / 256;
    const int gWave = (n + 3) / 4;
    const int gRow128 = (n + 127) / 128;

    // ---- layer 1 ----
    gemm128_bias<<<gRow128, 256, 0, stream>>>(xbuf, w1q, b1, nullptr, nullptr,
                                              hbuf, nullptr, n, 128);
    aggregate128_par<<<n, 256, 0, stream>>>(hbuf, dinv, nodeWf, startA, indeg, ssrc,
                                            xbuf, colsumS, n, E);
    bn_stats<<<512, 128, 0, stream>>>(xbuf, n, stats1, stats1 + 128);
    bn_apply_quant_u8<<<gElem128, 256, 0, stream>>>(xbuf, stats1, stats1 + 128,
                                                    bn1g, bn1b, g2, qbuf, n);

    // ---- layer 2: aggregate(q)*W + rowsum*b (stats fused into GEMM) ----
    aggregate_q8_wave<<<gWave, 256, 0, stream>>>(qbuf, dinv, g2, nodeWf, 1, startA, indeg,
                                                 ssrc, hbuf, n, E);
    gemm128_bias<<<gRow128, 256, 0, stream>>>(hbuf, w2q, b2, dinv, colsumS,
                                              xbuf, stats2, n, 128);
    bn_reduce<<<1, 256, 0, stream>>>(stats2);
    bn_apply_quant_u8<<<gElem128, 256, 0, stream>>>(xbuf, stats2, stats2 + 128,
                                                    bn2g, bn2b, g3, qbuf, n);

    // ---- layer 3: aggregate(q)*W3 + rowsum*b3, softmax fused ----
    aggregate_q8_wave<<<gWave, 256, 0, stream>>>(qbuf, dinv, g3, nodeWf, 2, startA, indeg,
                                                 ssrc, hbuf, n, E);
    gemm40_softmax<<<gRow128, 256, 0, stream>>>(hbuf, w3q, b3, dinv, colsumS,
                                                outF, n, C, 128);
}

// Round 14
// 493.903 us; speedup vs baseline: 1.1519x; 1.0179x over previous
//
#include <hip/hip_runtime.h>
#include <hip/hip_bf16.h>
#include <math.h>

#define QSTRIDE 144   // 128 code bytes + w2,w3 floats at 128,132 + 8 pad

// ---------------- graph structure ----------------

__global__ void count_indeg(const int* __restrict__ dst, int e, int* __restrict__ indeg) {
    int i = blockIdx.x * blockDim.x + threadIdx.x;
    if (i < e) atomicAdd(&indeg[dst[i]], 1);
}

// fused setup: dinv + ranges + embedded q-row weights (i < n) | weight fake-quant (i < nW)
__global__ void setup_misc(const int* __restrict__ indeg, float* __restrict__ dinv,
                           int* __restrict__ start, int* __restrict__ cursor,
                           int* __restrict__ counter,
                           const float* __restrict__ g2, const float* __restrict__ g3,
                           unsigned char* __restrict__ qbuf, int n,
                           const float* __restrict__ W1, const float* __restrict__ a1,
                           const float* __restrict__ W2, const float* __restrict__ a2,
                           const float* __restrict__ W3, const float* __restrict__ a3,
                           float* __restrict__ w1q, float* __restrict__ w2q,
                           float* __restrict__ w3q, int n1, int n2, int n3) {
    int i = blockIdx.x * blockDim.x + threadIdx.x;
    if (i < n) {
        int d = indeg[i];
        float ds = 1.0f / sqrtf((float)(d + 1));
        dinv[i] = ds;
        float2 wv = make_float2(ds * g2[i], ds * g3[i]);
        *(float2*)(qbuf + (size_t)i * QSTRIDE + 128) = wv;   // survives bn_apply (codes only)
        int s = atomicAdd(counter, d);
        start[i] = s;
        cursor[i] = s;
    }
    const float* w; const float* a; float* o; int k;
    if (i < n1) { w = W1; a = a1; o = w1q; k = i; }
    else if (i < n1 + n2) { w = W2; a = a2; o = w2q; k = i - n1; }
    else if (i < n1 + n2 + n3) { w = W3; a = a3; o = w3q; k = i - n1 - n2; }
    else return;
    float s = a[0];
    float v = w[k] / s;
    v = fminf(fmaxf(v, -8.0f), 7.0f);
    o[k] = rintf(v) * s;   // round-half-even, matches jnp.round
}

// minimal CSR fill: one atomic + one 4B store per edge
__global__ void fill_csr_min(const int* __restrict__ src, const int* __restrict__ dst,
                             int e, int* __restrict__ cursor, int* __restrict__ ssrc, int n) {
    int i = blockIdx.x * blockDim.x + threadIdx.x;
    if (i >= e) return;
    int s = src[i];
    int p = atomicAdd(&cursor[dst[i]], 1);
    if (p >= 0 && p < e) ssrc[p] = ((unsigned)s < (unsigned)n) ? s : -1;
}

// ---------------- GEMM 128-col + optional fused BN-stats partials ----------------

__global__ __launch_bounds__(256) void gemm128_bias(
        const float* __restrict__ A, const float* __restrict__ B,
        const float* __restrict__ bias,
        const float* __restrict__ dinv, const float* __restrict__ colsumS,
        float* __restrict__ C, float* __restrict__ statsP, int M, int K) {
    __shared__ float sA[16][132];
    __shared__ float sB[16][132];
    int tid = threadIdx.x;
    int rowBase = blockIdx.x * 128;
    int tx = tid & 15;
    int ty = tid >> 4;
    float acc[8][8] = {};

    int aRow = tid >> 1;
    int aK   = (tid & 1) * 8;
    int bK   = tid >> 4;
    int bCol = (tid & 15) * 8;

    for (int k0 = 0; k0 < K; k0 += 16) {
        int gRow = rowBase + aRow;
        if (gRow >= M) gRow = M - 1;
        const float* ap = A + (size_t)gRow * K + k0 + aK;
        float4 a0 = *(const float4*)ap;
        float4 a1 = *(const float4*)(ap + 4);
        sA[aK + 0][aRow] = a0.x;
        sA[aK + 1][aRow] = a0.y;
        sA[aK + 2][aRow] = a0.z;
        sA[aK + 3][aRow] = a0.w;
        sA[aK + 4][aRow] = a1.x;
        sA[aK + 5][aRow] = a1.y;
        sA[aK + 6][aRow] = a1.z;
        sA[aK + 7][aRow] = a1.w;
        const float* bp = B + (size_t)(k0 + bK) * 128 + bCol;
        *(float4*)&sB[bK][bCol]     = *(const float4*)bp;
        *(float4*)&sB[bK][bCol + 4] = *(const float4*)(bp + 4);
        __syncthreads();

#pragma unroll
        for (int kk = 0; kk < 16; ++kk) {
            float4 av0 = *(const float4*)&sA[kk][ty * 8];
            float4 av1 = *(const float4*)&sA[kk][ty * 8 + 4];
            float4 bv0 = *(const float4*)&sB[kk][tx * 4];
            float4 bv1 = *(const float4*)&sB[kk][64 + tx * 4];
            float a[8] = {av0.x, av0.y, av0.z, av0.w, av1.x, av1.y, av1.z, av1.w};
            float b[8] = {bv0.x, bv0.y, bv0.z, bv0.w, bv1.x, bv1.y, bv1.z, bv1.w};
#pragma unroll
            for (int i = 0; i < 8; ++i)
#pragma unroll
                for (int j = 0; j < 8; ++j)
                    acc[i][j] = fmaf(a[i], b[j], acc[i][j]);
        }
        __syncthreads();
    }

    int c0 = tx * 4, c1 = 64 + tx * 4;
    float bb[8];
#pragma unroll
    for (int j = 0; j < 4; ++j) { bb[j] = bias[c0 + j]; bb[4 + j] = bias[c1 + j]; }
    float s1[8] = {}, s2[8] = {};
#pragma unroll
    for (int i = 0; i < 8; ++i) {
        int row = rowBase + ty * 8 + i;
        if (row >= M) continue;
        float rs = 1.0f;
        if (dinv) { float di = dinv[row]; rs = di * di + colsumS[row]; }
        float v[8];
#pragma unroll
        for (int j = 0; j < 8; ++j) {
            v[j] = acc[i][j] + rs * bb[j];
            s1[j] += v[j];
            s2[j] += v[j] * v[j];
        }
        *(float4*)&C[(size_t)row * 128 + c0] = *(float4*)&v[0];
        *(float4*)&C[(size_t)row * 128 + c1] = *(float4*)&v[4];
    }
    if (statsP) {
        float* sp = statsP + (blockIdx.x & 63) * 256;
#pragma unroll
        for (int j = 0; j < 4; ++j) { sA[ty][c0 + j] = s1[j]; sA[ty][c1 + j] = s1[4 + j]; }
        __syncthreads();
        if (tid < 128) {
            float t = 0.f;
#pragma unroll
            for (int k = 0; k < 16; ++k) t += sA[k][tid];
            atomicAdd(&sp[tid], t);
        }
        __syncthreads();
#pragma unroll
        for (int j = 0; j < 4; ++j) { sA[ty][c0 + j] = s2[j]; sA[ty][c1 + j] = s2[4 + j]; }
        __syncthreads();
        if (tid < 128) {
            float t = 0.f;
#pragma unroll
            for (int k = 0; k < 16; ++k) t += sA[k][tid];
            atomicAdd(&sp[128 + tid], t);
        }
    }
}

// ---------------- layer-3 GEMM (N<=64) + fused log_softmax ----------------

__global__ __launch_bounds__(256) void gemm40_softmax(
        const float* __restrict__ A, const float* __restrict__ B,
        const float* __restrict__ bias,
        const float* __restrict__ dinv, const float* __restrict__ colsumS,
        float* __restrict__ out, int M, int N, int K) {
    __shared__ float sA[16][132];
    __shared__ float sB[16][68];
    __shared__ float sOut[128][41];
    int tid = threadIdx.x;
    int rowBase = blockIdx.x * 128;
    int tx = tid & 15;
    int ty = tid >> 4;
    float acc[8][4] = {};

    int aRow = tid >> 1;
    int aK   = (tid & 1) * 8;
    int bK   = tid >> 4;
    int bCol = (tid & 15) * 4;

    for (int k0 = 0; k0 < K; k0 += 16) {
        int gRow = rowBase + aRow;
        if (gRow >= M) gRow = M - 1;
        const float* ap = A + (size_t)gRow * K + k0 + aK;
        float4 a0 = *(const float4*)ap;
        float4 a1 = *(const float4*)(ap + 4);
        sA[aK + 0][aRow] = a0.x;
        sA[aK + 1][aRow] = a0.y;
        sA[aK + 2][aRow] = a0.z;
        sA[aK + 3][aRow] = a0.w;
        sA[aK + 4][aRow] = a1.x;
        sA[aK + 5][aRow] = a1.y;
        sA[aK + 6][aRow] = a1.z;
        sA[aK + 7][aRow] = a1.w;
#pragma unroll
        for (int j = 0; j < 4; ++j) {
            int col = bCol + j;
            sB[bK][col] = (col < N) ? B[(size_t)(k0 + bK) * N + col] : 0.0f;
        }
        __syncthreads();
#pragma unroll
        for (int kk = 0; kk < 16; ++kk) {
            float4 av0 = *(const float4*)&sA[kk][ty * 8];
            float4 av1 = *(const float4*)&sA[kk][ty * 8 + 4];
            float4 bv  = *(const float4*)&sB[kk][tx * 4];
            float a[8] = {av0.x, av0.y, av0.z, av0.w, av1.x, av1.y, av1.z, av1.w};
            float b[4] = {bv.x, bv.y, bv.z, bv.w};
#pragma unroll
            for (int i = 0; i < 8; ++i)
#pragma unroll
                for (int j = 0; j < 4; ++j)
                    acc[i][j] = fmaf(a[i], b[j], acc[i][j]);
        }
        __syncthreads();
    }

    int colOut = tx * 4;
    float bb[4];
#pragma unroll
    for (int j = 0; j < 4; ++j) bb[j] = (colOut + j < N) ? bias[colOut + j] : 0.0f;
#pragma unroll
    for (int i = 0; i < 8; ++i) {
        int rowL = ty * 8 + i;
        int row = rowBase + rowL;
        float rs = 1.0f;
        if (row < M) { float di = dinv[row]; rs = di * di + colsumS[row]; }
#pragma unroll
        for (int j = 0; j < 4; ++j)
            if (colOut + j < N) sOut[rowL][colOut + j] = acc[i][j] + rs * bb[j];
    }
    __syncthreads();
    if (tid < 128) {
        int row = rowBase + tid;
        if (row < M) {
            float mx = -INFINITY;
            for (int c = 0; c < N; ++c) mx = fmaxf(mx, sOut[tid][c]);
            float sm = 0.f;
            for (int c = 0; c < N; ++c) sm += expf(sOut[tid][c] - mx);
            float lg = mx + logf(sm);
            float* op = out + (size_t)row * N;
            for (int c = 0; c < N; ++c) op[c] = sOut[tid][c] - lg;
        }
    }
}

// ---------------- fp32 aggregation (layer 1): flat dinv staging + colsumS ----------------

__global__ __launch_bounds__(256) void aggregate128_par(
        const float* __restrict__ h, const float* __restrict__ dinv,
        const int* __restrict__ start, const int* __restrict__ indeg,
        const int* __restrict__ ssrc, float* __restrict__ out,
        float* __restrict__ colsumS, int n, int E) {
    __shared__ int   sIdx[256];
    __shared__ float sW[256];
    __shared__ float red[8][132];
    __shared__ float wpart[4];
    int node = blockIdx.x;
    int tid = threadIdx.x;
    int c4 = (tid & 31) * 4;
    int slot = tid >> 5;
    float di = dinv[node];
    int s0 = start[node];
    int len = indeg[node];
    if (s0 < 0) s0 = 0;
    if (len < 0) len = 0;
    if (s0 + len > E) len = (E - s0 > 0) ? (E - s0) : 0;

    float4 acc = {0.f, 0.f, 0.f, 0.f};
    float wacc = 0.f;
    for (int chunk = 0; chunk < len; chunk += 256) {
        int m = len - chunk; if (m > 256) m = 256;
        if (tid < m) {
            int s = ssrc[s0 + chunk + tid];
            float w;
            if ((unsigned)s >= (unsigned)n) { s = node; w = 0.f; }
            else w = dinv[s] * di;          // flat 200KB table: L2-resident
            sIdx[tid] = s; sW[tid] = w; wacc += w;
        }
        __syncthreads();
        int j = slot;
        for (; j + 8 < m; j += 16) {
            int sa = sIdx[j], sb = sIdx[j + 8];
            float wa = sW[j], wb = sW[j + 8];
            float4 va = *(const float4*)(h + (size_t)sa * 128 + c4);
            float4 vb = *(const float4*)(h + (size_t)sb * 128 + c4);
            acc.x = fmaf(va.x, wa, acc.x); acc.y = fmaf(va.y, wa, acc.y);
            acc.z = fmaf(va.z, wa, acc.z); acc.w = fmaf(va.w, wa, acc.w);
            acc.x = fmaf(vb.x, wb, acc.x); acc.y = fmaf(vb.y, wb, acc.y);
            acc.z = fmaf(vb.z, wb, acc.z); acc.w = fmaf(vb.w, wb, acc.w);
        }
        if (j < m) {
            int sa = sIdx[j];
            float wa = sW[j];
            float4 va = *(const float4*)(h + (size_t)sa * 128 + c4);
            acc.x = fmaf(va.x, wa, acc.x); acc.y = fmaf(va.y, wa, acc.y);
            acc.z = fmaf(va.z, wa, acc.z); acc.w = fmaf(va.w, wa, acc.w);
        }
        __syncthreads();
    }
#pragma unroll
    for (int o = 1; o < 64; o <<= 1) wacc += __shfl_xor(wacc, o);
    if ((tid & 63) == 0) wpart[tid >> 6] = wacc;
    *(float4*)&red[slot][c4] = acc;
    __syncthreads();
    if (tid == 0) colsumS[node] = wpart[0] + wpart[1] + wpart[2] + wpart[3];
    if (tid < 128) {
        int c = tid;
        float r = h[(size_t)node * 128 + c] * di * di;    // self loop
#pragma unroll
        for (int s = 0; s < 8; ++s) r += red[s][c];
        out[(size_t)node * 128 + c] = r;
    }
}

// ---------------- u8 aggregation (layers 2,3): one WAVE per node ----------------
// Row-embedded weights: chain is ssrc -> row gather only (weight in same row).

__device__ __forceinline__ void unpack_fma(float* acc, uint4 v, float w) {
    acc[0]  = fmaf((float)(v.x & 255), w, acc[0]);
    acc[1]  = fmaf((float)((v.x >> 8) & 255), w, acc[1]);
    acc[2]  = fmaf((float)((v.x >> 16) & 255), w, acc[2]);
    acc[3]  = fmaf((float)(v.x >> 24), w, acc[3]);
    acc[4]  = fmaf((float)(v.y & 255), w, acc[4]);
    acc[5]  = fmaf((float)((v.y >> 8) & 255), w, acc[5]);
    acc[6]  = fmaf((float)((v.y >> 16) & 255), w, acc[6]);
    acc[7]  = fmaf((float)(v.y >> 24), w, acc[7]);
    acc[8]  = fmaf((float)(v.z & 255), w, acc[8]);
    acc[9]  = fmaf((float)((v.z >> 8) & 255), w, acc[9]);
    acc[10] = fmaf((float)((v.z >> 16) & 255), w, acc[10]);
    acc[11] = fmaf((float)(v.z >> 24), w, acc[11]);
    acc[12] = fmaf((float)(v.w & 255), w, acc[12]);
    acc[13] = fmaf((float)((v.w >> 8) & 255), w, acc[13]);
    acc[14] = fmaf((float)((v.w >> 16) & 255), w, acc[14]);
    acc[15] = fmaf((float)(v.w >> 24), w, acc[15]);
}

__global__ __launch_bounds__(256) void aggregate_q8_wave(
        const unsigned char* __restrict__ q, const float* __restrict__ dinv,
        const float* __restrict__ gscale, int wOff,   // 128 (w2) or 132 (w3)
        const int* __restrict__ start, const int* __restrict__ indeg,
        const int* __restrict__ ssrc, float* __restrict__ out, int n, int E) {
    int node = blockIdx.x * 4 + (threadIdx.x >> 6);
    if (node >= n) return;
    int lane = threadIdx.x & 63;
    int slot = lane >> 3;      // 0..7
    int sl   = lane & 7;       // covers bytes sl*16..sl*16+15
    float di = dinv[node];
    int s0 = start[node];
    int len = indeg[node];
    if (s0 < 0) s0 = 0;
    if (len < 0) len = 0;
    if (s0 + len > E) len = (E - s0 > 0) ? (E - s0) : 0;

    float acc[16] = {};
    int j = slot;
    for (; j + 8 < len; j += 16) {
        int sa = ssrc[s0 + j];
        int sb = ssrc[s0 + j + 8];
        bool va_ok = (unsigned)sa < (unsigned)n;
        bool vb_ok = (unsigned)sb < (unsigned)n;
        if (!va_ok) sa = node;
        if (!vb_ok) sb = node;
        const unsigned char* ra = q + (size_t)sa * QSTRIDE;
        const unsigned char* rb = q + (size_t)sb * QSTRIDE;
        float wa = va_ok ? *(const float*)(ra + wOff) * di : 0.f;
        float wb = vb_ok ? *(const float*)(rb + wOff) * di : 0.f;
        uint4 va = *(const uint4*)(ra + sl * 16);
        uint4 vb = *(const uint4*)(rb + sl * 16);
        unpack_fma(acc, va, wa);
        unpack_fma(acc, vb, wb);
    }
    if (j < len) {
        int sa = ssrc[s0 + j];
        bool va_ok = (unsigned)sa < (unsigned)n;
        if (!va_ok) sa = node;
        const unsigned char* ra = q + (size_t)sa * QSTRIDE;
        float wa = va_ok ? *(const float*)(ra + wOff) * di : 0.f;
        uint4 va = *(const uint4*)(ra + sl * 16);
        unpack_fma(acc, va, wa);
    }
#pragma unroll
    for (int o = 8; o < 64; o <<= 1) {
#pragma unroll
        for (int k = 0; k < 16; ++k) acc[k] += __shfl_xor(acc[k], o);
    }
    if (slot == 0) {
        uint4 vs = *(const uint4*)(q + (size_t)node * QSTRIDE + sl * 16);
        unpack_fma(acc, vs, gscale[node] * di * di);   // self loop
        float* op = out + (size_t)node * 128 + sl * 16;
        *(float4*)(op + 0)  = *(float4*)&acc[0];
        *(float4*)(op + 4)  = *(float4*)&acc[4];
        *(float4*)(op + 8)  = *(float4*)&acc[8];
        *(float4*)(op + 12) = *(float4*)&acc[12];
    }
}

// ---------------- BatchNorm ----------------

__global__ void bn_stats(const float* __restrict__ x, int n,
                         float* __restrict__ sums, float* __restrict__ sumsq) {
    int c = threadIdx.x;   // 128
    float s = 0.f, s2 = 0.f;
    for (int r = blockIdx.x; r < n; r += gridDim.x) {
        float v = x[(size_t)r * 128 + c];
        s += v; s2 += v * v;
    }
    atomicAdd(&sums[c], s);
    atomicAdd(&sumsq[c], s2);
}

__global__ void bn_reduce(float* __restrict__ statsP) {
    int t = threadIdx.x;   // 256
    float s = 0.f;
    for (int k = 0; k < 64; ++k) s += statsP[k * 256 + t];
    __syncthreads();
    statsP[t] = s;
}

// BN finalize + affine + ReLU + 4-bit fake-quant -> u8 code into strided q rows
__global__ void bn_apply_quant_u8(const float* __restrict__ x,
                                  const float* __restrict__ sums,
                                  const float* __restrict__ sumsq,
                                  const float* __restrict__ g, const float* __restrict__ b,
                                  const float* __restrict__ gs,
                                  unsigned char* __restrict__ out, int n) {
    int idx = blockIdx.x * blockDim.x + threadIdx.x;
    if (idx >= n * 128) return;
    int c = idx & 127;
    int r = idx >> 7;
    float m  = sums[c] / (float)n;
    float vr = sumsq[c] / (float)n - m * m;
    float a  = g[c] * (1.0f / sqrtf(vr + 1e-5f));
    float bp = b[c] - m * a;
    float v = a * x[idx] + bp;
    v = fmaxf(v, 0.0f);
    float qv = fminf(fmaxf(v / gs[r], 0.0f), 15.0f);
    out[(size_t)r * QSTRIDE + c] = (unsigned char)rintf(qv);   // codes only; weights persist
}

// ---------------- launch ----------------

extern "C" void kernel_launch(void* const* d_in, const int* in_sizes, int n_in,
                              void* d_out, int out_size, void* d_ws, size_t ws_size,
                              hipStream_t stream) {
    float*       xbuf = (float*)d_in[0];          // reused as scratch after layer-1 GEMM
    const int*   ei   = (const int*)d_in[1];
    const float* W1   = (const float*)d_in[2];
    const float* b1   = (const float*)d_in[3];
    const float* a1   = (const float*)d_in[4];
    const float* W2   = (const float*)d_in[5];
    const float* b2   = (const float*)d_in[6];
    const float* a2   = (const float*)d_in[7];
    const float* g2   = (const float*)d_in[8];
    const float* W3   = (const float*)d_in[9];
    const float* b3   = (const float*)d_in[10];
    const float* a3   = (const float*)d_in[11];
    const float* g3   = (const float*)d_in[12];
    const float* bn1g = (const float*)d_in[13];
    const float* bn1b = (const float*)d_in[14];
    const float* bn2g = (const float*)d_in[15];
    const float* bn2b = (const float*)d_in[16];

    const int n = in_sizes[0] / 128;      // 50000
    const int E = in_sizes[1] / 2;        // 800000
    const int C = in_sizes[9] / 128;      // 40
    const int* src = ei;
    const int* dst = ei + E;

    // ---- workspace layout: zeroed region FIRST ----
    char* wsp = (char*)d_ws;
    size_t off = 0;
    auto take = [&](size_t bytes) -> void* {
        void* p = wsp + off;
        off += (bytes + 255) & ~(size_t)255;
        return p;
    };
    int*   indeg   = (int*)take((size_t)n * 4);
    int*   counter = (int*)take(4);
    float* stats1  = (float*)take(256 * 4);          // layer-1: sums | sumsq
    float* stats2  = (float*)take(64 * 256 * 4);     // layer-2: 64 partial copies
    size_t zeroBytes = off;
    int*   startA  = (int*)take((size_t)n * 4);
    int*   cursor  = (int*)take((size_t)n * 4);
    float* dinv    = (float*)take((size_t)n * 4);
    float* colsumS = (float*)take((size_t)n * 4);
    int*   ssrc    = (int*)take((size_t)E * 4);
    float* w1q     = (float*)take(128 * 128 * 4);
    float* w2q     = (float*)take(128 * 128 * 4);
    float* w3q     = (float*)take((size_t)128 * C * 4);
    unsigned char* qbuf = (unsigned char*)take((size_t)n * QSTRIDE);
    float* hbuf    = (float*)take((size_t)n * 128 * 4);

    float* outF  = (float*)d_out;

    // ---- setup ----
    hipMemsetAsync(d_ws, 0, zeroBytes, stream);
    count_indeg<<<(E + 255) / 256, 256, 0, stream>>>(dst, E, indeg);
    const int nW = 128 * 128 + 128 * 128 + 128 * C;
    int setupN = (n > nW) ? n : nW;
    setup_misc<<<(setupN + 255) / 256, 256, 0, stream>>>(
        indeg, dinv, startA, cursor, counter, g2, g3, qbuf, n,
        W1, a1, W2, a2, W3, a3, w1q, w2q, w3q, 128 * 128, 128 * 128, 128 * C);
    fill_csr_min<<<(E + 255) / 256, 256, 0, stream>>>(src, dst, E, cursor, ssrc, n);

    const int gElem128 = (n * 128 + 255) / 256;
    const int gWave = (n + 3) / 4;
    const int gRow128 = (n + 127) / 128;

    // ---- layer 1 ----
    gemm128_bias<<<gRow128, 256, 0, stream>>>(xbuf, w1q, b1, nullptr, nullptr,
                                              hbuf, nullptr, n, 128);
    aggregate128_par<<<n, 256, 0, stream>>>(hbuf, dinv, startA, indeg, ssrc,
                                            xbuf, colsumS, n, E);
    bn_stats<<<512, 128, 0, stream>>>(xbuf, n, stats1, stats1 + 128);
    bn_apply_quant_u8<<<gElem128, 256, 0, stream>>>(xbuf, stats1, stats1 + 128,
                                                    bn1g, bn1b, g2, qbuf, n);

    // ---- layer 2: aggregate(q)*W + rowsum*b (stats fused into GEMM) ----
    aggregate_q8_wave<<<gWave, 256, 0, stream>>>(qbuf, dinv, g2, 128, startA, indeg,
                                                 ssrc, hbuf, n, E);
    gemm128_bias<<<gRow128, 256, 0, stream>>>(hbuf, w2q, b2, dinv, colsumS,
                                              xbuf, stats2, n, 128);
    bn_reduce<<<1, 256, 0, stream>>>(stats2);
    bn_apply_quant_u8<<<gElem128, 256, 0, stream>>>(xbuf, stats2, stats2 + 128,
                                                    bn2g, bn2b, g3, qbuf, n);

    // ---- layer 3: aggregate(q)*W3 + rowsum*b3, softmax fused ----
    aggregate_q8_wave<<<gWave, 256, 0, stream>>>(qbuf, dinv, g3, 132, startA, indeg,
                                                 ssrc, hbuf, n, E);
    gemm40_softmax<<<gRow128, 256, 0, stream>>>(hbuf, w3q, b3, dinv, colsumS,
                                                outF, n, C, 128);
}